// Round 1
// baseline (1001.696 us; speedup 1.0000x reference)
//
#include <hip/hip_runtime.h>

typedef __attribute__((ext_vector_type(8))) short bf16x8;
typedef __attribute__((ext_vector_type(4))) float f32x4;

static __device__ __forceinline__ unsigned short f2bf(float f) {
    union { float f; unsigned u; } v; v.f = f;
    return (unsigned short)((v.u + 0x7FFFu + ((v.u >> 16) & 1u)) >> 16);
}

// Wp[ch=4][rs=9][oc=256][cw=32] bf16, value = weight[oc][ch*32+cw][r][s] * wscale
__global__ void prep_weights(const float* __restrict__ w, unsigned short* __restrict__ wp) {
    int t = blockIdx.x * 256 + threadIdx.x;      // 0..294911
    const float wscale = 0.02946278254943948f;   // 1/sqrt(3*3*128)
    int cw = t & 31;
    int oc = (t >> 5) & 255;
    int cr = t >> 13;          // 0..35
    int ch = cr / 9;
    int rs = cr - ch * 9;
    int r  = rs / 3;
    int s  = rs - r * 3;
    int c  = ch * 32 + cw;
    wp[t] = f2bf(w[((oc * 128 + c) * 3 + r) * 3 + s] * wscale);
}

// wg: 512 thr = 8 waves (2m x 4n), tile = 128 pixels (8h x 16w) x 256 oc.
// Per 32-ch chunk: separable fp32 blur -> swizzled LDS bf16 tile, then 9 rs x MFMA.
__global__ __launch_bounds__(512, 4)
void conv_blur_mfma(const float* __restrict__ x, const unsigned short* __restrict__ wp,
                    const float* __restrict__ bias, float* __restrict__ out) {
    // blurred tile: [bi=17][bj=33] pixels, 96 B per pixel (32 bf16 ch + swizzle pad)
    __shared__ __align__(16) unsigned char lds[17 * 33 * 96];

    const int bx = blockIdx.x;
    const int n  = bx >> 7;          // image
    const int tt = bx & 127;
    const int u0 = (tt >> 3) * 8;    // out-row origin
    const int v0 = (tt & 7) * 16;    // out-col origin

    const int tid  = threadIdx.x;
    const int lane = tid & 63;
    const int wid  = tid >> 6;
    const int wm   = wid >> 2;       // 0..1 : pixel-block
    const int wn   = wid & 3;        // 0..3 : oc-block
    const int g    = lane >> 4;      // 0..3 : k-group
    const int wq   = lane & 15;

    f32x4 acc[4][4];
    #pragma unroll
    for (int i = 0; i < 4; ++i)
        #pragma unroll
        for (int j = 0; j < 4; ++j)
            acc[i][j] = (f32x4){0.f, 0.f, 0.f, 0.f};

    for (int ch = 0; ch < 4; ++ch) {
        __syncthreads();   // protect previous chunk's reads before overwrite
        // ---- blur stage: item = (c, bj) column, separable 4-tap H then V ----
        for (int item = tid; item < 1056; item += 512) {
            int c  = item / 33;
            int bj = item - c * 33;
            const float* xp = x + (size_t)((n * 128) + ch * 32 + c) * (256 * 256);
            int xc0 = 2 * v0 + bj - 2;      // leftmost x col (pad=2)
            float xh[20];
            #pragma unroll
            for (int row = 0; row < 20; ++row) {
                int xr = 2 * u0 + row - 2;
                float a0 = 0.f, a1 = 0.f, a2 = 0.f, a3 = 0.f;
                if (xr >= 0 && xr < 256) {
                    const float* rp = xp + xr * 256;
                    if ((unsigned)xc0 <= 252u) {
                        a0 = rp[xc0]; a1 = rp[xc0 + 1]; a2 = rp[xc0 + 2]; a3 = rp[xc0 + 3];
                    } else {
                        if ((unsigned)(xc0 + 0) < 256u) a0 = rp[xc0 + 0];
                        if ((unsigned)(xc0 + 1) < 256u) a1 = rp[xc0 + 1];
                        if ((unsigned)(xc0 + 2) < 256u) a2 = rp[xc0 + 2];
                        if ((unsigned)(xc0 + 3) < 256u) a3 = rp[xc0 + 3];
                    }
                }
                xh[row] = (a0 + 3.f * (a1 + a2) + a3) * 0.125f;
            }
            // write slot-swizzled so MFMA A-reads are bank-conflict-free
            int sb = (((c >> 3) ^ ((bj >> 1) & 3)) << 4) + (c & 7) * 2;
            #pragma unroll
            for (int bi = 0; bi < 17; ++bi) {
                float bv = (xh[bi] + 3.f * (xh[bi + 1] + xh[bi + 2]) + xh[bi + 3]) * 0.125f;
                *(unsigned short*)(lds + (bi * 33 + bj) * 96 + sb) = f2bf(bv);
            }
        }
        __syncthreads();
        // ---- MFMA stage: 9 rs positions, B-frags straight from global (L2) ----
        #pragma unroll
        for (int rs = 0; rs < 9; ++rs) {
            const int r = rs / 3, s = rs - r * 3;
            bf16x8 bfrag[4];
            #pragma unroll
            for (int nf = 0; nf < 4; ++nf) {
                int oc = wn * 64 + nf * 16 + wq;
                bfrag[nf] = *(const bf16x8*)(wp + ((size_t)((ch * 9 + rs) * 256 + oc)) * 32 + g * 8);
            }
            #pragma unroll
            for (int mf = 0; mf < 4; ++mf) {
                int bi = 2 * (wm * 4 + mf) + r;
                int bj = 2 * wq + s;
                bf16x8 afrag = *(const bf16x8*)(lds + (bi * 33 + bj) * 96 +
                                                ((g ^ ((bj >> 1) & 3)) << 4));
                #pragma unroll
                for (int nf = 0; nf < 4; ++nf)
                    acc[mf][nf] = __builtin_amdgcn_mfma_f32_16x16x32_bf16(
                        afrag, bfrag[nf], acc[mf][nf], 0, 0, 0);
            }
        }
    }

    // ---- epilogue: transpose via per-wave LDS region, coalesced f32x4 stores ----
    const float gain = 1.4142135623730951f;   // sqrt(2)
    float* ldsf = (float*)(lds + wid * 4352); // per-wave [16 oc][68 f32]
    #pragma unroll 1
    for (int nf = 0; nf < 4; ++nf) {
        __syncthreads();
        #pragma unroll
        for (int mf = 0; mf < 4; ++mf)
            *(f32x4*)(ldsf + wq * 68 + mf * 16 + g * 4) = acc[mf][nf];
        __syncthreads();
        #pragma unroll
        for (int q = 0; q < 4; ++q) {
            int ocl = q * 4 + g;
            f32x4 v = *(const f32x4*)(ldsf + ocl * 68 + wq * 4);
            int ocg = wn * 64 + nf * 16 + ocl;
            float b = bias[ocg];              // LR_MUL = 1
            int u  = u0 + wm * 4 + (wq >> 2);
            int vv = v0 + (wq & 3) * 4;
            f32x4 o;
            #pragma unroll
            for (int i = 0; i < 4; ++i) {
                float z = v[i] + b;
                z = (z >= 0.f ? z : 0.2f * z) * gain;
                o[i] = fminf(fmaxf(z, -256.f), 256.f);
            }
            *(f32x4*)(out + (((size_t)n * 256 + ocg) * 128 + u) * 128 + vv) = o;
        }
    }
}

extern "C" void kernel_launch(void* const* d_in, const int* in_sizes, int n_in,
                              void* d_out, int out_size, void* d_ws, size_t ws_size,
                              hipStream_t stream) {
    const float* x    = (const float*)d_in[0];
    const float* w    = (const float*)d_in[1];
    const float* bias = (const float*)d_in[2];
    unsigned short* wp = (unsigned short*)d_ws;   // 589,824 B
    float* out = (float*)d_out;

    prep_weights<<<1152, 256, 0, stream>>>(w, wp);
    conv_blur_mfma<<<2048, 512, 0, stream>>>(x, wp, bias, out);
}

// Round 2
// 700.667 us; speedup vs baseline: 1.4296x; 1.4296x over previous
//
#include <hip/hip_runtime.h>

typedef __attribute__((ext_vector_type(8))) short bf16x8;
typedef __attribute__((ext_vector_type(4))) float f32x4;

static __device__ __forceinline__ unsigned short f2bf(float f) {
    union { float f; unsigned u; } v; v.f = f;
    return (unsigned short)((v.u + 0x7FFFu + ((v.u >> 16) & 1u)) >> 16);
}

// Wp[ch=4][rs=9][oc=256][cw=32] bf16, value = weight[oc][ch*32+cw][r][s] * wscale
__global__ void prep_weights(const float* __restrict__ w, unsigned short* __restrict__ wp) {
    int t = blockIdx.x * 256 + threadIdx.x;      // 0..294911
    const float wscale = 0.02946278254943948f;   // 1/sqrt(3*3*128)
    int cw = t & 31;
    int oc = (t >> 5) & 255;
    int cr = t >> 13;          // 0..35
    int ch = cr / 9;
    int rs = cr - ch * 9;
    int r  = rs / 3;
    int s  = rs - r * 3;
    int c  = ch * 32 + cw;
    wp[t] = f2bf(w[((oc * 128 + c) * 3 + r) * 3 + s] * wscale);
}

// wg: 512 thr = 8 waves (2m x 4n), tile = 128 pixels (8h x 16w) x 256 oc.
// Per 32-ch chunk: separable fp32 blur -> swizzled LDS bf16 tile, then 9 rs x MFMA.
__global__ __launch_bounds__(512, 4)
void conv_blur_mfma(const float* __restrict__ x, const unsigned short* __restrict__ wp,
                    const float* __restrict__ bias, float* __restrict__ out) {
    // blurred tile: [bi=17][bj=33] pixels, 96 B per pixel (32 bf16 ch + swizzle pad)
    __shared__ __align__(16) unsigned char lds[17 * 33 * 96];

    const int bx = blockIdx.x;
    const int n  = bx >> 7;          // image
    const int tt = bx & 127;
    const int u0 = (tt >> 3) * 8;    // out-row origin
    const int v0 = (tt & 7) * 16;    // out-col origin

    const int tid  = threadIdx.x;
    const int lane = tid & 63;
    const int wid  = tid >> 6;
    const int wm   = wid >> 2;       // 0..1 : pixel-block (u)
    const int wn   = wid & 3;        // 0..3 : oc-block
    const int g    = lane >> 4;      // 0..3 : k-group
    const int wq   = lane & 15;

    f32x4 acc[4][4];
    #pragma unroll
    for (int i = 0; i < 4; ++i)
        #pragma unroll
        for (int j = 0; j < 4; ++j)
            acc[i][j] = (f32x4){0.f, 0.f, 0.f, 0.f};

    for (int ch = 0; ch < 4; ++ch) {
        __syncthreads();   // protect previous chunk's reads before overwrite
        // ---- blur stage: item = (channel-pair k, column bj); rolling 4-row window ----
        for (int item = tid; item < 528; item += 512) {
            int k  = item / 33;              // 0..15 -> channels 2k, 2k+1
            int bj = item - k * 33;
            const float* xp0 = x + (size_t)(n * 128 + ch * 32 + 2 * k) * 65536;
            const float* xp1 = xp0 + 65536;
            int xc0 = 2 * v0 + bj - 2;       // leftmost x col (pad=2)
            bool incol = ((unsigned)xc0 <= 252u);
            // swizzled byte offset within a pixel row: slot = (c>>3) ^ ((bj>>2)&3)
            unsigned off = (unsigned)bj * 96u
                         + ((((unsigned)k >> 2) ^ (((unsigned)bj >> 2) & 3u)) << 4)
                         + ((unsigned)(k & 3)) * 4u;
            float h0[20], h1[20];
            #pragma unroll
            for (int row = 0; row < 20; ++row) {
                int xr = 2 * u0 + row - 2;
                float a0 = 0.f, a1 = 0.f, a2 = 0.f, a3 = 0.f;
                float b0 = 0.f, b1 = 0.f, b2 = 0.f, b3 = 0.f;
                if ((unsigned)xr < 256u) {
                    const float* rp0 = xp0 + (xr << 8) + xc0;
                    const float* rp1 = xp1 + (xr << 8) + xc0;
                    if (incol) {
                        a0 = rp0[0]; a1 = rp0[1]; a2 = rp0[2]; a3 = rp0[3];
                        b0 = rp1[0]; b1 = rp1[1]; b2 = rp1[2]; b3 = rp1[3];
                    } else {
                        if ((unsigned)(xc0 + 0) < 256u) { a0 = rp0[0]; b0 = rp1[0]; }
                        if ((unsigned)(xc0 + 1) < 256u) { a1 = rp0[1]; b1 = rp1[1]; }
                        if ((unsigned)(xc0 + 2) < 256u) { a2 = rp0[2]; b2 = rp1[2]; }
                        if ((unsigned)(xc0 + 3) < 256u) { a3 = rp0[3]; b3 = rp1[3]; }
                    }
                }
                h0[row] = (a0 + 3.f * (a1 + a2) + a3) * 0.125f;
                h1[row] = (b0 + 3.f * (b1 + b2) + b3) * 0.125f;
                if (row >= 3) {
                    float bv0 = (h0[row - 3] + 3.f * (h0[row - 2] + h0[row - 1]) + h0[row]) * 0.125f;
                    float bv1 = (h1[row - 3] + 3.f * (h1[row - 2] + h1[row - 1]) + h1[row]) * 0.125f;
                    unsigned pk = (unsigned)f2bf(bv0) | ((unsigned)f2bf(bv1) << 16);
                    *(unsigned*)(lds + (unsigned)(row - 3) * 3168u + off) = pk;
                }
            }
        }
        __syncthreads();
        // ---- MFMA stage: 9 rs positions, B-frags straight from global (L2) ----
        #pragma unroll
        for (int rs = 0; rs < 9; ++rs) {
            const int r = rs / 3, s = rs - r * 3;
            bf16x8 bfrag[4];
            #pragma unroll
            for (int nf = 0; nf < 4; ++nf) {
                int oc = wn * 64 + nf * 16 + wq;
                bfrag[nf] = *(const bf16x8*)(wp + ((size_t)((ch * 9 + rs) * 256 + oc)) * 32 + g * 8);
            }
            #pragma unroll
            for (int mf = 0; mf < 4; ++mf) {
                int bi = 2 * (wm * 4 + mf) + r;
                int bj = 2 * wq + s;
                bf16x8 afrag = *(const bf16x8*)(lds + (bi * 33 + bj) * 96 +
                                                ((g ^ ((bj >> 2) & 3)) << 4));
                #pragma unroll
                for (int nf = 0; nf < 4; ++nf)
                    acc[mf][nf] = __builtin_amdgcn_mfma_f32_16x16x32_bf16(
                        afrag, bfrag[nf], acc[mf][nf], 0, 0, 0);
            }
        }
    }

    // ---- epilogue: transpose via per-wave LDS region, coalesced f32x4 stores ----
    const float gain = 1.4142135623730951f;   // sqrt(2)
    float* ldsf = (float*)(lds + wid * 4352); // per-wave [16 oc][68 f32]
    #pragma unroll
    for (int nf = 0; nf < 4; ++nf) {
        __syncthreads();
        #pragma unroll
        for (int mf = 0; mf < 4; ++mf)
            *(f32x4*)(ldsf + wq * 68 + mf * 16 + g * 4) = acc[mf][nf];
        __syncthreads();
        #pragma unroll
        for (int q = 0; q < 4; ++q) {
            int ocl = q * 4 + g;
            f32x4 v = *(const f32x4*)(ldsf + ocl * 68 + wq * 4);
            int ocg = wn * 64 + nf * 16 + ocl;
            float b = bias[ocg];              // LR_MUL = 1
            int u  = u0 + wm * 4 + (wq >> 2);
            int vv = v0 + (wq & 3) * 4;
            f32x4 o;
            #pragma unroll
            for (int i = 0; i < 4; ++i) {
                float z = v[i] + b;
                z = (z >= 0.f ? z : 0.2f * z) * gain;
                o[i] = fminf(fmaxf(z, -256.f), 256.f);
            }
            *(f32x4*)(out + (((size_t)n * 256 + ocg) * 128 + u) * 128 + vv) = o;
        }
    }
}

extern "C" void kernel_launch(void* const* d_in, const int* in_sizes, int n_in,
                              void* d_out, int out_size, void* d_ws, size_t ws_size,
                              hipStream_t stream) {
    const float* x    = (const float*)d_in[0];
    const float* w    = (const float*)d_in[1];
    const float* bias = (const float*)d_in[2];
    unsigned short* wp = (unsigned short*)d_ws;   // 589,824 B
    float* out = (float*)d_out;

    prep_weights<<<1152, 256, 0, stream>>>(w, wp);
    conv_blur_mfma<<<2048, 512, 0, stream>>>(x, wp, bias, out);
}

// Round 3
// 524.831 us; speedup vs baseline: 1.9086x; 1.3350x over previous
//
#include <hip/hip_runtime.h>

typedef __attribute__((ext_vector_type(8))) short bf16x8;
typedef __attribute__((ext_vector_type(4))) float f32x4;

static __device__ __forceinline__ unsigned short f2bf(float f) {
    union { float f; unsigned u; } v; v.f = f;
    return (unsigned short)((v.u + 0x7FFFu + ((v.u >> 16) & 1u)) >> 16);
}

// Wp[ch=4][rs=9][oc=256][cw=32] bf16, value = weight[oc][ch*32+cw][r][s] * wscale
__global__ void prep_weights(const float* __restrict__ w, unsigned short* __restrict__ wp) {
    int t = blockIdx.x * 256 + threadIdx.x;      // 0..294911
    const float wscale = 0.02946278254943948f;   // 1/sqrt(3*3*128)
    int cw = t & 31;
    int oc = (t >> 5) & 255;
    int cr = t >> 13;          // 0..35
    int ch = cr / 9;
    int rs = cr - ch * 9;
    int r  = rs / 3;
    int s  = rs - r * 3;
    int c  = ch * 32 + cw;
    wp[t] = f2bf(w[((oc * 128 + c) * 3 + r) * 3 + s] * wscale);
}

// wg: 512 thr = 8 waves (2m x 4n), tile = 128 pixels (8h x 16w) x 256 oc.
// Per 32-ch chunk: separable fp32 blur -> swizzled LDS bf16 tile, then 3x3 MFMA.
__global__ __launch_bounds__(512, 4)
void conv_blur_mfma(const float* __restrict__ x, const unsigned short* __restrict__ wp,
                    const float* __restrict__ bias, float* __restrict__ out) {
    // blurred tile: [bi=17][bj=33] pixels, 96 B per pixel (32 bf16 ch + swizzle pad)
    __shared__ __align__(16) unsigned char lds[17 * 33 * 96];

    const int bx = blockIdx.x;
    const int n  = bx >> 7;          // image
    const int tt = bx & 127;
    const int u0 = (tt >> 3) * 8;    // out-row origin
    const int v0 = (tt & 7) * 16;    // out-col origin

    const int tid  = threadIdx.x;
    const int lane = tid & 63;
    const int wid  = tid >> 6;
    const int wm   = wid >> 2;       // 0..1 : pixel-block (u)
    const int wn   = wid & 3;        // 0..3 : oc-block
    const int g    = lane >> 4;      // 0..3 : k-group
    const int wq   = lane & 15;

    // per-lane weight pointer: wp + (oc_base + wq)*32 + g*8 ; nf steps via 1KB imm
    const unsigned short* wpL = wp + (size_t)(wn * 64 + wq) * 32 + g * 8;

    f32x4 acc[4][4];
    #pragma unroll
    for (int i = 0; i < 4; ++i)
        #pragma unroll
        for (int j = 0; j < 4; ++j)
            acc[i][j] = (f32x4){0.f, 0.f, 0.f, 0.f};

    for (int ch = 0; ch < 4; ++ch) {
        __syncthreads();   // protect previous chunk's reads before overwrite
        // ---- blur stage: item = (channel-pair k, column bj); rolling 4-row window ----
        for (int item = tid; item < 528; item += 512) {
            int k  = item / 33;              // 0..15 -> channels 2k, 2k+1
            int bj = item - k * 33;
            const float* xp0 = x + (size_t)(n * 128 + ch * 32 + 2 * k) * 65536;
            const float* xp1 = xp0 + 65536;
            int xc0 = 2 * v0 + bj - 2;       // leftmost x col (pad=2)
            bool incol = ((unsigned)xc0 <= 252u);
            // swizzled byte offset within a pixel row: slot = (c>>3) ^ ((bj>>2)&3)
            unsigned off = (unsigned)bj * 96u
                         + ((((unsigned)k >> 2) ^ (((unsigned)bj >> 2) & 3u)) << 4)
                         + ((unsigned)(k & 3)) * 4u;
            float h0[20], h1[20];
            #pragma unroll
            for (int row = 0; row < 20; ++row) {
                int xr = 2 * u0 + row - 2;
                float a0 = 0.f, a1 = 0.f, a2 = 0.f, a3 = 0.f;
                float b0 = 0.f, b1 = 0.f, b2 = 0.f, b3 = 0.f;
                if ((unsigned)xr < 256u) {
                    const float* rp0 = xp0 + (xr << 8) + xc0;
                    const float* rp1 = xp1 + (xr << 8) + xc0;
                    if (incol) {
                        a0 = rp0[0]; a1 = rp0[1]; a2 = rp0[2]; a3 = rp0[3];
                        b0 = rp1[0]; b1 = rp1[1]; b2 = rp1[2]; b3 = rp1[3];
                    } else {
                        if ((unsigned)(xc0 + 0) < 256u) { a0 = rp0[0]; b0 = rp1[0]; }
                        if ((unsigned)(xc0 + 1) < 256u) { a1 = rp0[1]; b1 = rp1[1]; }
                        if ((unsigned)(xc0 + 2) < 256u) { a2 = rp0[2]; b2 = rp1[2]; }
                        if ((unsigned)(xc0 + 3) < 256u) { a3 = rp0[3]; b3 = rp1[3]; }
                    }
                }
                h0[row] = (a0 + 3.f * (a1 + a2) + a3) * 0.125f;
                h1[row] = (b0 + 3.f * (b1 + b2) + b3) * 0.125f;
                if (row >= 3) {
                    float bv0 = (h0[row - 3] + 3.f * (h0[row - 2] + h0[row - 1]) + h0[row]) * 0.125f;
                    float bv1 = (h1[row - 3] + 3.f * (h1[row - 2] + h1[row - 1]) + h1[row]) * 0.125f;
                    unsigned pk = (unsigned)f2bf(bv0) | ((unsigned)f2bf(bv1) << 16);
                    *(unsigned*)(lds + (unsigned)(row - 3) * 3168u + off) = pk;
                }
            }
        }
        __syncthreads();
        // ---- MFMA stage: 3x3 taps, unroll 1 to cap live registers ----
        const unsigned short* wpc = wpL + (size_t)ch * 9 * 8192;
        #pragma unroll 1
        for (int r = 0; r < 3; ++r) {
            #pragma unroll 1
            for (int s = 0; s < 3; ++s) {
                bf16x8 b0 = *(const bf16x8*)(wpc + 0 * 512);
                bf16x8 b1 = *(const bf16x8*)(wpc + 1 * 512);
                bf16x8 b2 = *(const bf16x8*)(wpc + 2 * 512);
                bf16x8 b3 = *(const bf16x8*)(wpc + 3 * 512);
                wpc += 8192;
                int bj  = 2 * wq + s;
                unsigned cb = (unsigned)bj * 96u + ((unsigned)(g ^ ((bj >> 2) & 3)) << 4);
                #pragma unroll
                for (int mf = 0; mf < 4; ++mf) {
                    int bi = 2 * (wm * 4 + mf) + r;
                    bf16x8 afrag = *(const bf16x8*)(lds + (unsigned)bi * 3168u + cb);
                    acc[mf][0] = __builtin_amdgcn_mfma_f32_16x16x32_bf16(afrag, b0, acc[mf][0], 0, 0, 0);
                    acc[mf][1] = __builtin_amdgcn_mfma_f32_16x16x32_bf16(afrag, b1, acc[mf][1], 0, 0, 0);
                    acc[mf][2] = __builtin_amdgcn_mfma_f32_16x16x32_bf16(afrag, b2, acc[mf][2], 0, 0, 0);
                    acc[mf][3] = __builtin_amdgcn_mfma_f32_16x16x32_bf16(afrag, b3, acc[mf][3], 0, 0, 0);
                }
            }
        }
    }

    // ---- epilogue: transpose via per-wave LDS region, coalesced f32x4 stores ----
    const float gain = 1.4142135623730951f;   // sqrt(2)
    float* ldsf = (float*)(lds + wid * 4352); // per-wave [16 oc][68 f32]
    #pragma unroll
    for (int nf = 0; nf < 4; ++nf) {
        __syncthreads();
        #pragma unroll
        for (int mf = 0; mf < 4; ++mf)
            *(f32x4*)(ldsf + wq * 68 + mf * 16 + g * 4) = acc[mf][nf];
        __syncthreads();
        #pragma unroll
        for (int q = 0; q < 4; ++q) {
            int ocl = q * 4 + g;
            f32x4 v = *(const f32x4*)(ldsf + ocl * 68 + wq * 4);
            int ocg = wn * 64 + nf * 16 + ocl;
            float b = bias[ocg];              // LR_MUL = 1
            int u  = u0 + wm * 4 + (wq >> 2);
            int vv = v0 + (wq & 3) * 4;
            f32x4 o;
            #pragma unroll
            for (int i = 0; i < 4; ++i) {
                float z = v[i] + b;
                z = (z >= 0.f ? z : 0.2f * z) * gain;
                o[i] = fminf(fmaxf(z, -256.f), 256.f);
            }
            *(f32x4*)(out + (((size_t)n * 256 + ocg) * 128 + u) * 128 + vv) = o;
        }
    }
}

extern "C" void kernel_launch(void* const* d_in, const int* in_sizes, int n_in,
                              void* d_out, int out_size, void* d_ws, size_t ws_size,
                              hipStream_t stream) {
    const float* x    = (const float*)d_in[0];
    const float* w    = (const float*)d_in[1];
    const float* bias = (const float*)d_in[2];
    unsigned short* wp = (unsigned short*)d_ws;   // 589,824 B
    float* out = (float*)d_out;

    prep_weights<<<1152, 256, 0, stream>>>(w, wp);
    conv_blur_mfma<<<2048, 512, 0, stream>>>(x, wp, bias, out);
}